// Round 7
// baseline (349.550 us; speedup 1.0000x reference)
//
#include <hip/hip_runtime.h>

#define N_TOK 8192
#define DDIM 1024
#define ODIM 1024
#define NEXP 8

typedef __attribute__((ext_vector_type(8))) short bf16x8;
typedef __attribute__((ext_vector_type(4))) float f32x4;

__device__ __forceinline__ unsigned int f2bf(float f) {
    unsigned int u = __float_as_uint(f);
    return (u + 0x7fffu + ((u >> 16) & 1u)) >> 16;  // RNE
}
__device__ __forceinline__ float bflo(unsigned int u) { return __uint_as_float(u << 16); }
__device__ __forceinline__ float bfhi(unsigned int u) { return __uint_as_float(u & 0xffff0000u); }

// ---------------- We [E,D,O] fp32 -> WeT [E,O,D] bf16 ----------------
__global__ __launch_bounds__(256) void wet_kernel(const float* __restrict__ We,
                                                  unsigned short* __restrict__ WeT) {
    __shared__ float tile[64][65];
    const int e = blockIdx.z, d0 = blockIdx.x * 64, o0 = blockIdx.y * 64;
    const int tid = threadIdx.x;
#pragma unroll
    for (int p = 0; p < 4; ++p) {
        int idx = p * 256 + tid;
        int row = idx >> 4, c = idx & 15;
        float4 v = *(const float4*)&We[(((size_t)e * 1024 + d0 + row) << 10) + o0 + (c << 2)];
        tile[row][c * 4 + 0] = v.x; tile[row][c * 4 + 1] = v.y;
        tile[row][c * 4 + 2] = v.z; tile[row][c * 4 + 3] = v.w;
    }
    __syncthreads();
#pragma unroll
    for (int p = 0; p < 2; ++p) {
        int idx = p * 256 + tid;
        int orow = idx >> 3, c8 = idx & 7;
        unsigned int u[8];
#pragma unroll
        for (int j = 0; j < 8; ++j) u[j] = f2bf(tile[c8 * 8 + j][orow]);
        uint4 q;
        q.x = u[0] | (u[1] << 16); q.y = u[2] | (u[3] << 16);
        q.z = u[4] | (u[5] << 16); q.w = u[6] | (u[7] << 16);
        *(uint4*)&WeT[(((size_t)e * 1024 + o0 + orow) << 10) + d0 + (c8 << 3)] = q;
    }
}

// ---------------- gating: one token per wave; emits x as bf16; zeroes counts ----------------
__global__ __launch_bounds__(256) void gate_kernel(const float* __restrict__ x,
                                                   const float* __restrict__ Wg,
                                                   const float* __restrict__ bg,
                                                   int* __restrict__ ea, int* __restrict__ eb,
                                                   float* __restrict__ ga, float* __restrict__ gb,
                                                   unsigned short* __restrict__ xbf,
                                                   int* __restrict__ counts) {
    if (blockIdx.x == 0) counts[threadIdx.x] = 0;  // zero all 8*32 padded counters
    const int wave = threadIdx.x >> 6, lane = threadIdx.x & 63;
    const int t = blockIdx.x * 4 + wave;
    const float* xr = x + (size_t)t * DDIM;

    float4 v[4];
#pragma unroll
    for (int c = 0; c < 4; ++c) v[c] = *(const float4*)&xr[c * 256 + lane * 4];

    unsigned short* xo = xbf + (size_t)t * DDIM;
#pragma unroll
    for (int c = 0; c < 4; ++c) {
        uint2 w;
        w.x = f2bf(v[c].x) | (f2bf(v[c].y) << 16);
        w.y = f2bf(v[c].z) | (f2bf(v[c].w) << 16);
        *(uint2*)&xo[c * 256 + lane * 4] = w;
    }

    float acc[8] = {0, 0, 0, 0, 0, 0, 0, 0};
#pragma unroll
    for (int c = 0; c < 4; ++c) {
        const int dbase = c * 256 + lane * 4;
#pragma unroll
        for (int j = 0; j < 4; ++j) {
            float xv = ((const float*)&v[c])[j];
            const float4* w = (const float4*)(Wg + (size_t)(dbase + j) * 8);
            float4 w0 = w[0], w1 = w[1];
            acc[0] += xv * w0.x; acc[1] += xv * w0.y; acc[2] += xv * w0.z; acc[3] += xv * w0.w;
            acc[4] += xv * w1.x; acc[5] += xv * w1.y; acc[6] += xv * w1.z; acc[7] += xv * w1.w;
        }
    }
#pragma unroll
    for (int off = 32; off > 0; off >>= 1) {
#pragma unroll
        for (int j = 0; j < 8; ++j) acc[j] += __shfl_xor(acc[j], off, 64);
    }
    if (lane == 0) {
        float s[8];
#pragma unroll
        for (int e = 0; e < 8; ++e) s[e] = acc[e] + bg[e];
        int a = 0;
#pragma unroll
        for (int e = 1; e < 8; ++e) if (s[e] > s[a]) a = e;
        int b = (a == 0) ? 1 : 0;
#pragma unroll
        for (int e = 0; e < 8; ++e) if (e != a && e != b && s[e] > s[b]) b = e;
        float g0 = 1.0f / (1.0f + __expf(s[b] - s[a]));  // renormed top-2 softmax
        ea[t] = a; eb[t] = b; ga[t] = g0; gb[t] = 1.0f - g0;
    }
}

// ---------------- bucket scatter: wave-ballot aggregation; records slots ----------------
__global__ __launch_bounds__(64) void scatter_kernel(const int* __restrict__ ea,
                                                     const int* __restrict__ eb,
                                                     int* __restrict__ counts,
                                                     int* __restrict__ btok,
                                                     int* __restrict__ slotA,
                                                     int* __restrict__ slotB) {
    const int t = blockIdx.x * 64 + threadIdx.x;  // grid = 128 blocks x 1 wave
    const int lane = threadIdx.x & 63;
#pragma unroll
    for (int pass = 0; pass < 2; ++pass) {
        const int e = (pass == 0) ? ea[t] : eb[t];
        int* slot = (pass == 0) ? slotA : slotB;
#pragma unroll
        for (int ex = 0; ex < NEXP; ++ex) {
            unsigned long long mask = __ballot(e == ex);
            if (mask) {
                int leader = __ffsll((long long)mask) - 1;
                int base = 0;
                if (lane == leader) base = atomicAdd(&counts[ex * 32], __popcll(mask));
                base = __shfl(base, leader, 64);
                if (e == ex) {
                    int pos = base + __popcll(mask & ((1ull << lane) - 1ull));
                    btok[ex * N_TOK + pos] = t;
                    slot[t] = ex * N_TOK + pos;
                }
            }
        }
    }
}

// ---------------- grouped expert GEMM, 128x128 tile, direct-to-register fragments ----------------
// K is contiguous for BOTH operands (xbf[token][d], WeT[o][d]); an MFMA fragment is
// 8 consecutive k elems = one 16-B global load per lane. No LDS staging, no K-loop
// barriers: MFMA interleaves with loads under compiler-scheduled fine-grained vmcnt.
__global__ __launch_bounds__(256) void moe_gemm(const unsigned short* __restrict__ xbf,
                                                const unsigned short* __restrict__ WeT,
                                                const float* __restrict__ be,
                                                const int* __restrict__ counts,
                                                const int* __restrict__ btok,
                                                unsigned short* __restrict__ ybuf) {
    const int e = blockIdx.z;
    const int cnt = counts[e * 32];
    const int r0 = blockIdx.y * 128;
    if (r0 >= cnt) return;
    const int n0 = blockIdx.x * 128;

    __shared__ int s_tok[128];
    const int tid = threadIdx.x;
    if (tid < 128) {
        int r = r0 + tid;
        int rc = (r < cnt) ? r : (cnt - 1);
        s_tok[tid] = btok[e * N_TOK + rc];
    }
    __syncthreads();

    const int wave = tid >> 6, lane = tid & 63;
    const int wm = (wave >> 1) * 64, wn = (wave & 1) * 64;
    const int quad = lane >> 4, rA = lane & 15;

    const unsigned short* aptr[4];
    const unsigned short* bptr[4];
#pragma unroll
    for (int mi = 0; mi < 4; ++mi)
        aptr[mi] = xbf + ((size_t)s_tok[wm + mi * 16 + rA] << 10) + quad * 8;
#pragma unroll
    for (int ni = 0; ni < 4; ++ni)
        bptr[ni] = WeT + (((size_t)e * 1024 + n0 + wn + ni * 16 + rA) << 10) + quad * 8;

    f32x4 acc[4][4];
#pragma unroll
    for (int mi = 0; mi < 4; ++mi)
#pragma unroll
        for (int ni = 0; ni < 4; ++ni) acc[mi][ni] = (f32x4){0.f, 0.f, 0.f, 0.f};

    for (int kb = 0; kb < DDIM; kb += 256) {  // 4 iterations, 8 unrolled k-steps each
#pragma unroll
        for (int ks = 0; ks < 8; ++ks) {
            const int ko = kb + ks * 32;
            bf16x8 af[4], bfr[4];
#pragma unroll
            for (int mi = 0; mi < 4; ++mi) af[mi] = *(const bf16x8*)(aptr[mi] + ko);
#pragma unroll
            for (int ni = 0; ni < 4; ++ni) bfr[ni] = *(const bf16x8*)(bptr[ni] + ko);
#pragma unroll
            for (int mi = 0; mi < 4; ++mi)
#pragma unroll
                for (int ni = 0; ni < 4; ++ni)
                    acc[mi][ni] = __builtin_amdgcn_mfma_f32_16x16x32_bf16(af[mi], bfr[ni], acc[mi][ni], 0, 0, 0);
        }
    }

    // epilogue: D[row = quad*4+reg][col = rA]; bias add, bf16 store (no atomics)
#pragma unroll
    for (int ni = 0; ni < 4; ++ni) {
        int col = n0 + wn + ni * 16 + rA;
        float bias = be[(e << 10) + col];
#pragma unroll
        for (int mi = 0; mi < 4; ++mi) {
#pragma unroll
            for (int r = 0; r < 4; ++r) {
                int lrow = wm + mi * 16 + quad * 4 + r;
                if (r0 + lrow < cnt) {
                    ybuf[(((size_t)e * N_TOK + r0 + lrow) << 10) + col] =
                        (unsigned short)f2bf(acc[mi][ni][r] + bias);
                }
            }
        }
    }
}

// ---------------- combine: out[t] = ga*yA[t] + gb*yB[t] ----------------
__global__ __launch_bounds__(256) void combine_kernel(const unsigned short* __restrict__ ybuf,
                                                      const int* __restrict__ slotA,
                                                      const int* __restrict__ slotB,
                                                      const float* __restrict__ ga,
                                                      const float* __restrict__ gb,
                                                      float* __restrict__ out) {
    const int wave = threadIdx.x >> 6, lane = threadIdx.x & 63;
    const int t = blockIdx.x * 4 + wave;
    const unsigned short* ra = ybuf + ((size_t)slotA[t] << 10);
    const unsigned short* rb = ybuf + ((size_t)slotB[t] << 10);
    const float a = ga[t], b = gb[t];
    float* orow = out + ((size_t)t << 10);
#pragma unroll
    for (int i = 0; i < 4; ++i) {
        int c = i * 256 + lane * 4;
        uint2 ua = *(const uint2*)&ra[c];
        uint2 ub = *(const uint2*)&rb[c];
        float4 o;
        o.x = a * bflo(ua.x) + b * bflo(ub.x);
        o.y = a * bfhi(ua.x) + b * bfhi(ub.x);
        o.z = a * bflo(ua.y) + b * bflo(ub.y);
        o.w = a * bfhi(ua.y) + b * bfhi(ub.y);
        *(float4*)&orow[c] = o;
    }
}

extern "C" void kernel_launch(void* const* d_in, const int* in_sizes, int n_in,
                              void* d_out, int out_size, void* d_ws, size_t ws_size,
                              hipStream_t stream) {
    const float* x  = (const float*)d_in[0];
    const float* We = (const float*)d_in[1];
    const float* be = (const float*)d_in[2];
    const float* Wg = (const float*)d_in[3];
    const float* bg = (const float*)d_in[4];
    float* out = (float*)d_out;

    char* ws = (char*)d_ws;
    size_t off = 0;
    int* counts = (int*)(ws + off); off += 8 * 32 * 4;            // 1 KB, padded 128 B/counter
    int* btok   = (int*)(ws + off); off += NEXP * N_TOK * 4;      // 256 KB
    int* slotA  = (int*)(ws + off); off += N_TOK * 4;
    int* slotB  = (int*)(ws + off); off += N_TOK * 4;
    int* ea = (int*)(ws + off); off += N_TOK * 4;
    int* eb = (int*)(ws + off); off += N_TOK * 4;
    float* ga = (float*)(ws + off); off += N_TOK * 4;
    float* gb = (float*)(ws + off); off += N_TOK * 4;
    unsigned short* WeT  = (unsigned short*)(ws + off); off += (size_t)NEXP * DDIM * ODIM * 2;  // 16.78 MB
    unsigned short* xbf  = (unsigned short*)(ws + off); off += (size_t)N_TOK * DDIM * 2;        // 16.78 MB
    unsigned short* ybuf = (unsigned short*)(ws + off); off += (size_t)NEXP * N_TOK * ODIM * 2; // 33.55 MB (slot-sparse)

    wet_kernel<<<dim3(16, 16, 8), 256, 0, stream>>>(We, WeT);
    gate_kernel<<<dim3(N_TOK / 4), 256, 0, stream>>>(x, Wg, bg, ea, eb, ga, gb, xbf, counts);
    scatter_kernel<<<dim3(N_TOK / 64), 64, 0, stream>>>(ea, eb, counts, btok, slotA, slotB);
    moe_gemm<<<dim3(ODIM / 128, N_TOK / 128, NEXP), 256, 0, stream>>>(xbf, WeT, be, counts, btok, ybuf);
    combine_kernel<<<dim3(N_TOK / 4), 256, 0, stream>>>(ybuf, slotA, slotB, ga, gb, out);
}

// Round 8
// 233.515 us; speedup vs baseline: 1.4969x; 1.4969x over previous
//
#include <hip/hip_runtime.h>

#define N_TOK 8192
#define DDIM 1024
#define ODIM 1024
#define NEXP 8

typedef __attribute__((ext_vector_type(8))) short bf16x8;
typedef __attribute__((ext_vector_type(4))) float f32x4;

__device__ __forceinline__ unsigned int f2bf(float f) {
    unsigned int u = __float_as_uint(f);
    return (u + 0x7fffu + ((u >> 16) & 1u)) >> 16;  // RNE
}
__device__ __forceinline__ float bflo(unsigned int u) { return __uint_as_float(u << 16); }
__device__ __forceinline__ float bfhi(unsigned int u) { return __uint_as_float(u & 0xffff0000u); }

__device__ __forceinline__ void async_copy16(const unsigned short* g, unsigned short* l) {
    __builtin_amdgcn_global_load_lds(
        (const __attribute__((address_space(1))) unsigned int*)g,
        (__attribute__((address_space(3))) unsigned int*)l, 16, 0, 0);
}

// ---------------- fused prep: gate (blocks 0..2047) + We transpose (blocks 2048..4095) ----------
__global__ __launch_bounds__(256) void prep_kernel(const float* __restrict__ x,
                                                   const float* __restrict__ Wg,
                                                   const float* __restrict__ bg,
                                                   const float* __restrict__ We,
                                                   int* __restrict__ ea, int* __restrict__ eb,
                                                   float* __restrict__ ga, float* __restrict__ gb,
                                                   unsigned short* __restrict__ xbf,
                                                   unsigned short* __restrict__ WeT,
                                                   int* __restrict__ counts) {
    __shared__ float tile[64][65];
    if (blockIdx.x < 2048) {
        // ---- gate: one token per wave; emits x as bf16; zeroes counts ----
        if (blockIdx.x == 0) counts[threadIdx.x] = 0;  // 8*32 padded counters
        const int wave = threadIdx.x >> 6, lane = threadIdx.x & 63;
        const int t = blockIdx.x * 4 + wave;
        const float* xr = x + (size_t)t * DDIM;

        float4 v[4];
#pragma unroll
        for (int c = 0; c < 4; ++c) v[c] = *(const float4*)&xr[c * 256 + lane * 4];

        unsigned short* xo = xbf + (size_t)t * DDIM;
#pragma unroll
        for (int c = 0; c < 4; ++c) {
            uint2 w;
            w.x = f2bf(v[c].x) | (f2bf(v[c].y) << 16);
            w.y = f2bf(v[c].z) | (f2bf(v[c].w) << 16);
            *(uint2*)&xo[c * 256 + lane * 4] = w;
        }

        float acc[8] = {0, 0, 0, 0, 0, 0, 0, 0};
#pragma unroll
        for (int c = 0; c < 4; ++c) {
            const int dbase = c * 256 + lane * 4;
#pragma unroll
            for (int j = 0; j < 4; ++j) {
                float xv = ((const float*)&v[c])[j];
                const float4* w = (const float4*)(Wg + (size_t)(dbase + j) * 8);
                float4 w0 = w[0], w1 = w[1];
                acc[0] += xv * w0.x; acc[1] += xv * w0.y; acc[2] += xv * w0.z; acc[3] += xv * w0.w;
                acc[4] += xv * w1.x; acc[5] += xv * w1.y; acc[6] += xv * w1.z; acc[7] += xv * w1.w;
            }
        }
#pragma unroll
        for (int off = 32; off > 0; off >>= 1) {
#pragma unroll
            for (int j = 0; j < 8; ++j) acc[j] += __shfl_xor(acc[j], off, 64);
        }
        if (lane == 0) {
            float s[8];
#pragma unroll
            for (int e = 0; e < 8; ++e) s[e] = acc[e] + bg[e];
            int a = 0;
#pragma unroll
            for (int e = 1; e < 8; ++e) if (s[e] > s[a]) a = e;
            int b = (a == 0) ? 1 : 0;
#pragma unroll
            for (int e = 0; e < 8; ++e) if (e != a && e != b && s[e] > s[b]) b = e;
            float g0 = 1.0f / (1.0f + __expf(s[b] - s[a]));  // renormed top-2 softmax
            ea[t] = a; eb[t] = b; ga[t] = g0; gb[t] = 1.0f - g0;
        }
    } else {
        // ---- We [E,D,O] fp32 -> WeT [E,O,D] bf16, 64x64 tiles ----
        const int lin = blockIdx.x - 2048;
        const int e = lin >> 8, rem = lin & 255;
        const int d0 = (rem >> 4) * 64, o0 = (rem & 15) * 64;
        const int tid = threadIdx.x;
#pragma unroll
        for (int p = 0; p < 4; ++p) {
            int idx = p * 256 + tid;
            int row = idx >> 4, c = idx & 15;
            float4 v = *(const float4*)&We[(((size_t)e * 1024 + d0 + row) << 10) + o0 + (c << 2)];
            tile[row][c * 4 + 0] = v.x; tile[row][c * 4 + 1] = v.y;
            tile[row][c * 4 + 2] = v.z; tile[row][c * 4 + 3] = v.w;
        }
        __syncthreads();
#pragma unroll
        for (int p = 0; p < 2; ++p) {
            int idx = p * 256 + tid;
            int orow = idx >> 3, c8 = idx & 7;
            unsigned int u[8];
#pragma unroll
            for (int j = 0; j < 8; ++j) u[j] = f2bf(tile[c8 * 8 + j][orow]);
            uint4 q;
            q.x = u[0] | (u[1] << 16); q.y = u[2] | (u[3] << 16);
            q.z = u[4] | (u[5] << 16); q.w = u[6] | (u[7] << 16);
            *(uint4*)&WeT[(((size_t)e * 1024 + o0 + orow) << 10) + d0 + (c8 << 3)] = q;
        }
    }
}

// ---------------- bucket scatter: wave-ballot aggregation; records slots ----------------
__global__ __launch_bounds__(64) void scatter_kernel(const int* __restrict__ ea,
                                                     const int* __restrict__ eb,
                                                     int* __restrict__ counts,
                                                     int* __restrict__ btok,
                                                     int* __restrict__ slotA,
                                                     int* __restrict__ slotB) {
    const int t = blockIdx.x * 64 + threadIdx.x;  // grid = 128 blocks x 1 wave
    const int lane = threadIdx.x & 63;
#pragma unroll
    for (int pass = 0; pass < 2; ++pass) {
        const int e = (pass == 0) ? ea[t] : eb[t];
        int* slot = (pass == 0) ? slotA : slotB;
#pragma unroll
        for (int ex = 0; ex < NEXP; ++ex) {
            unsigned long long mask = __ballot(e == ex);
            if (mask) {
                int leader = __ffsll((long long)mask) - 1;
                int base = 0;
                if (lane == leader) base = atomicAdd(&counts[ex * 32], __popcll(mask));
                base = __shfl(base, leader, 64);
                if (e == ex) {
                    int pos = base + __popcll(mask & ((1ull << lane) - 1ull));
                    btok[ex * N_TOK + pos] = t;
                    slot[t] = ex * N_TOK + pos;
                }
            }
        }
    }
}

// ---------------- grouped expert GEMM, 128x128 tile, BK=64, XOR-swizzled LDS ----------------
// 1-D grid, id = y*64 + n*8 + e: with round-robin XCD placement, each expert is pinned
// to one XCD (its 2 MB WeT slice becomes L2-resident) and the 8 n-tiles sharing an
// A-tile run temporally adjacent on that XCD (A fetched ~once per y).
__global__ __launch_bounds__(256) void moe_gemm(const unsigned short* __restrict__ xbf,
                                                const unsigned short* __restrict__ WeT,
                                                const float* __restrict__ be,
                                                const int* __restrict__ counts,
                                                const int* __restrict__ btok,
                                                unsigned short* __restrict__ ybuf) {
    const int id = blockIdx.x;
    const int e = id & 7;
    const int n0 = ((id >> 3) & 7) * 128;
    const int r0 = (id >> 6) * 128;
    const int cnt = counts[e * 32];
    if (r0 >= cnt) return;

    __shared__ unsigned short sA[128 * 64];
    __shared__ unsigned short sB[128 * 64];
    __shared__ int s_tok[128];

    const int tid = threadIdx.x;
    if (tid < 128) {
        int r = r0 + tid;
        int rc = (r < cnt) ? r : (cnt - 1);
        s_tok[tid] = btok[e * N_TOK + rc];
    }
    const int wave = tid >> 6, lane = tid & 63;
    __syncthreads();

    // staging: lane L -> row w*32+p*8+(L>>3), global chunk (L&7)^(L>>3)
    const int colo = (((lane & 7) ^ (lane >> 3)) * 8);
    size_t a_off[4];
    size_t b_off[4];
#pragma unroll
    for (int p = 0; p < 4; ++p) {
        int row = wave * 32 + p * 8 + (lane >> 3);
        a_off[p] = ((size_t)s_tok[row] << 10) + colo;
        b_off[p] = (((size_t)e * 1024 + n0 + row) << 10) + colo;
    }

    const int wm = (wave >> 1) * 64, wn = (wave & 1) * 64;
    const int quad = lane >> 4, rA = lane & 15;
    const int sw = rA & 7;  // swizzle key for fragment reads

    f32x4 acc[4][4];
#pragma unroll
    for (int mi = 0; mi < 4; ++mi)
#pragma unroll
        for (int ni = 0; ni < 4; ++ni) acc[mi][ni] = (f32x4){0.f, 0.f, 0.f, 0.f};

    for (int kb = 0; kb < DDIM; kb += 64) {
#pragma unroll
        for (int p = 0; p < 4; ++p) {
            unsigned short* la = &sA[(wave * 32 + p * 8) * 64];
            unsigned short* lb = &sB[(wave * 32 + p * 8) * 64];
            async_copy16(xbf + a_off[p] + kb, la);
            async_copy16(WeT + b_off[p] + kb, lb);
        }
        __syncthreads();
#pragma unroll
        for (int ks = 0; ks < 2; ++ks) {
            const int cslot = ((ks * 4 + quad) ^ sw) * 8;  // swizzled chunk offset (elems)
            bf16x8 af[4], bfr[4];
#pragma unroll
            for (int mi = 0; mi < 4; ++mi)
                af[mi] = *(bf16x8*)&sA[(wm + mi * 16 + rA) * 64 + cslot];
#pragma unroll
            for (int ni = 0; ni < 4; ++ni)
                bfr[ni] = *(bf16x8*)&sB[(wn + ni * 16 + rA) * 64 + cslot];
#pragma unroll
            for (int mi = 0; mi < 4; ++mi)
#pragma unroll
                for (int ni = 0; ni < 4; ++ni)
                    acc[mi][ni] = __builtin_amdgcn_mfma_f32_16x16x32_bf16(af[mi], bfr[ni], acc[mi][ni], 0, 0, 0);
        }
        __syncthreads();
    }

    // epilogue: D[row = quad*4+reg][col = rA]; bias add, bf16 store (no atomics)
#pragma unroll
    for (int ni = 0; ni < 4; ++ni) {
        int col = n0 + wn + ni * 16 + rA;
        float bias = be[(e << 10) + col];
#pragma unroll
        for (int mi = 0; mi < 4; ++mi) {
#pragma unroll
            for (int r = 0; r < 4; ++r) {
                int lrow = wm + mi * 16 + quad * 4 + r;
                if (r0 + lrow < cnt) {
                    ybuf[(((size_t)e * N_TOK + r0 + lrow) << 10) + col] =
                        (unsigned short)f2bf(acc[mi][ni][r] + bias);
                }
            }
        }
    }
}

// ---------------- combine: out[t] = ga*yA[t] + gb*yB[t] ----------------
__global__ __launch_bounds__(256) void combine_kernel(const unsigned short* __restrict__ ybuf,
                                                      const int* __restrict__ slotA,
                                                      const int* __restrict__ slotB,
                                                      const float* __restrict__ ga,
                                                      const float* __restrict__ gb,
                                                      float* __restrict__ out) {
    const int wave = threadIdx.x >> 6, lane = threadIdx.x & 63;
    const int t = blockIdx.x * 4 + wave;
    const unsigned short* ra = ybuf + ((size_t)slotA[t] << 10);
    const unsigned short* rb = ybuf + ((size_t)slotB[t] << 10);
    const float a = ga[t], b = gb[t];
    float* orow = out + ((size_t)t << 10);
#pragma unroll
    for (int i = 0; i < 2; ++i) {
        int c = i * 512 + lane * 8;
        uint4 ua = *(const uint4*)&ra[c];
        uint4 ub = *(const uint4*)&rb[c];
        float4 o0, o1;
        o0.x = a * bflo(ua.x) + b * bflo(ub.x);
        o0.y = a * bfhi(ua.x) + b * bfhi(ub.x);
        o0.z = a * bflo(ua.y) + b * bflo(ub.y);
        o0.w = a * bfhi(ua.y) + b * bfhi(ub.y);
        o1.x = a * bflo(ua.z) + b * bflo(ub.z);
        o1.y = a * bfhi(ua.z) + b * bfhi(ub.z);
        o1.z = a * bflo(ua.w) + b * bflo(ub.w);
        o1.w = a * bfhi(ua.w) + b * bfhi(ub.w);
        *(float4*)&orow[c] = o0;
        *(float4*)&orow[c + 4] = o1;
    }
}

extern "C" void kernel_launch(void* const* d_in, const int* in_sizes, int n_in,
                              void* d_out, int out_size, void* d_ws, size_t ws_size,
                              hipStream_t stream) {
    const float* x  = (const float*)d_in[0];
    const float* We = (const float*)d_in[1];
    const float* be = (const float*)d_in[2];
    const float* Wg = (const float*)d_in[3];
    const float* bg = (const float*)d_in[4];
    float* out = (float*)d_out;

    char* ws = (char*)d_ws;
    size_t off = 0;
    int* counts = (int*)(ws + off); off += 8 * 32 * 4;            // 1 KB, padded 128 B/counter
    int* btok   = (int*)(ws + off); off += NEXP * N_TOK * 4;      // 256 KB
    int* slotA  = (int*)(ws + off); off += N_TOK * 4;
    int* slotB  = (int*)(ws + off); off += N_TOK * 4;
    int* ea = (int*)(ws + off); off += N_TOK * 4;
    int* eb = (int*)(ws + off); off += N_TOK * 4;
    float* ga = (float*)(ws + off); off += N_TOK * 4;
    float* gb = (float*)(ws + off); off += N_TOK * 4;
    unsigned short* WeT  = (unsigned short*)(ws + off); off += (size_t)NEXP * DDIM * ODIM * 2;  // 16.78 MB
    unsigned short* xbf  = (unsigned short*)(ws + off); off += (size_t)N_TOK * DDIM * 2;        // 16.78 MB
    unsigned short* ybuf = (unsigned short*)(ws + off); off += (size_t)NEXP * N_TOK * ODIM * 2; // 33.55 MB (slot-sparse)

    prep_kernel<<<dim3(4096), 256, 0, stream>>>(x, Wg, bg, We, ea, eb, ga, gb, xbf, WeT, counts);
    scatter_kernel<<<dim3(N_TOK / 64), 64, 0, stream>>>(ea, eb, counts, btok, slotA, slotB);
    moe_gemm<<<dim3(64 * 8 * 8), 256, 0, stream>>>(xbf, WeT, be, counts, btok, ybuf);
    combine_kernel<<<dim3(N_TOK / 4), 256, 0, stream>>>(ybuf, slotA, slotB, ga, gb, out);
}